// Round 19
// baseline (95.849 us; speedup 1.0000x reference)
//
#include <hip/hip_runtime.h>
#include <hip/hip_bf16.h>
#include <math.h>

// Problem constants: S=4, B=1, C=128, h=w=d=10 -> N=1000, L=4000, nL=2, H=8, Dh=16
#define LL 4000
#define CC 128
#define NN 1000
#define NLAYER 2
#define KSPLIT 4                        // == S; split-K aligned to sequences
#define SCLOG2 0.36067376022224085f    // 0.25 * log2(e), folded into Q
#define KROW 20                        // padded LDS row (shorts) for K tile [32][KROW]
#define VROW 36                        // padded LDS row (shorts) for V^T tile [16][VROW]

typedef __attribute__((ext_vector_type(4))) short bf16x4;
typedef __attribute__((ext_vector_type(8))) short short8;
typedef __attribute__((ext_vector_type(4))) float f32x4;
typedef __attribute__((ext_vector_type(2))) unsigned int u32x2;

__device__ __forceinline__ short bf16rne(float f) {
    return __builtin_bit_cast(short, __float2bfloat16(f));
}
__device__ __forceinline__ float bf16tof(short s) {
    return __builtin_bit_cast(float, (unsigned)((unsigned short)s) << 16);
}

// pack 4 f32 -> 4 bf16 (truncate) via 2x v_perm_b32
__device__ __forceinline__ bf16x4 pack4(const float* p) {
    unsigned w01 = __builtin_amdgcn_perm(__builtin_bit_cast(unsigned, p[1]),
                                         __builtin_bit_cast(unsigned, p[0]),
                                         0x07060302u);
    unsigned w23 = __builtin_amdgcn_perm(__builtin_bit_cast(unsigned, p[3]),
                                         __builtin_bit_cast(unsigned, p[2]),
                                         0x07060302u);
    u32x2 w = {w01, w23};
    return __builtin_bit_cast(bf16x4, w);
}

// ---------------------------------------------------------------------------
// merged preamble (all-coalesced): blocks 0..255 = weight 32x32 tile
// transposes; block 256 = kbw; blocks 257..768 = tokenize LDS-transpose.
__global__ __launch_bounds__(256) void prep_tok_kernel(
        const float* __restrict__ Wq, const float* __restrict__ Wk,
        const float* __restrict__ Wv, const float* __restrict__ Wp,
        const float* __restrict__ w1, const float* __restrict__ w2,
        const float* __restrict__ r, const float* __restrict__ beta,
        short* __restrict__ wt8, short* __restrict__ w1t,
        short* __restrict__ w2t, float* __restrict__ kbw,
        const float* __restrict__ z, const float* __restrict__ se,
        float* __restrict__ tok, short* __restrict__ tokb) {
    __shared__ float tl[32][33];
    const int bid = blockIdx.x;
    const int tx = threadIdx.x & 31, ty = threadIdx.x >> 5;
    if (bid < 256) {
        const float* src;
        short* dst;
        int K, N, k0, n0;
        if (bid < 128) {
            int m = bid >> 4, t = bid & 15;
            src = (m < 2) ? Wq + (size_t)m * 16384
                : (m < 4) ? Wk + (size_t)(m - 2) * 16384
                : (m < 6) ? Wv + (size_t)(m - 4) * 16384
                          : Wp + (size_t)(m - 6) * 16384;
            dst = wt8 + (size_t)m * 16384;
            K = 128; N = 128; k0 = (t >> 2) * 32; n0 = (t & 3) * 32;
        } else if (bid < 192) {
            int t = bid - 128;
            src = w1; dst = w1t;
            K = 128; N = 512; k0 = (t >> 4) * 32; n0 = (t & 15) * 32;
        } else {
            int t = bid - 192;
            src = w2; dst = w2t;
            K = 512; N = 128; k0 = (t >> 2) * 32; n0 = (t & 3) * 32;
        }
        #pragma unroll
        for (int i = 0; i < 4; ++i)
            tl[ty * 4 + i][tx] = src[(size_t)(k0 + ty * 4 + i) * N + n0 + tx];
        __syncthreads();
        #pragma unroll
        for (int i = 0; i < 4; ++i)
            dst[(size_t)(n0 + ty * 4 + i) * K + k0 + tx] = bf16rne(tl[tx][ty * 4 + i]);
    } else if (bid == 256) {
        int i = threadIdx.x;
        if (i < NLAYER * KSPLIT) {
            int l = i / KSPLIT, zz = i - l * KSPLIT;
            kbw[i] = exp2f(beta[l] * __log2f(r[zz]));
        }
    } else {
        int b2 = bid - 257;
        const int n0 = (b2 & 31) * 32;
        const int c0 = ((b2 >> 5) & 3) * 32;
        const int s  = b2 >> 7;
        #pragma unroll
        for (int i = 0; i < 4; ++i) {
            int n = n0 + tx;
            if (n < NN) tl[ty * 4 + i][tx] = z[((size_t)s * CC + c0 + ty * 4 + i) * NN + n];
        }
        __syncthreads();
        #pragma unroll
        for (int i = 0; i < 4; ++i) {
            int n = n0 + ty * 4 + i;
            if (n < NN) {
                int c = c0 + tx;
                float v = tl[tx][ty * 4 + i] + se[s * CC + c];
                size_t o = ((size_t)(s * NN + n)) * CC + c;
                tok[o] = v;
                tokb[o] = bf16rne(v);
            }
        }
    }
}

// ---------------------------------------------------------------------------
// MFMA GEMM body (16-row tile): out[M,N] = act(A@Wt^T + bias)
// flags: 1 = bf16 out, 2 = exact GELU, 4 = bf16 transposed out [N][M],
//        8 = *SCLOG2, 16 = bf16 head-major out [N/16][M][16]
__device__ __forceinline__ void gemm_body(
        const short* __restrict__ A, const short* __restrict__ Wt,
        const float* __restrict__ bias, void* __restrict__ outp,
        int M, int K, int N, int flags, int row0, int col0) {
    __shared__ short Al[16][136];
    __shared__ short Wl[128][136];
    const int tid = threadIdx.x;
    const int lane = tid & 63;
    const int w = tid >> 6;
    const int lq = lane & 15, g = lane >> 4;

    f32x4 acc[2] = {{0.f,0.f,0.f,0.f},{0.f,0.f,0.f,0.f}};

    for (int kc = 0; kc < K; kc += 128) {
        {
            int r = tid >> 4, c = (tid & 15) * 8;
            *(short8*)&Al[r][c] = *(const short8*)(A + (size_t)(row0 + r) * K + kc + c);
        }
        {
            int c = (tid & 15) * 8;
            int nb = tid >> 4;
            #pragma unroll
            for (int i = 0; i < 8; ++i) {
                int n = nb + i * 16;
                *(short8*)&Wl[n][c] = *(const short8*)(Wt + (size_t)(col0 + n) * K + kc + c);
            }
        }
        __syncthreads();
        bf16x4 af[8];
        #pragma unroll
        for (int ks = 0; ks < 8; ++ks)
            af[ks] = *(const bf16x4*)&Al[lq][ks * 16 + g * 4];
        #pragma unroll
        for (int ct = 0; ct < 2; ++ct) {
            int n = (w * 2 + ct) * 16 + lq;
            #pragma unroll
            for (int ks = 0; ks < 8; ++ks) {
                bf16x4 bfr = *(const bf16x4*)&Wl[n][ks * 16 + g * 4];
                acc[ct] = __builtin_amdgcn_mfma_f32_16x16x16bf16_1k(af[ks], bfr, acc[ct], 0, 0, 0);
            }
        }
        __syncthreads();
    }
    #pragma unroll
    for (int ct = 0; ct < 2; ++ct) {
        int col = col0 + (w * 2 + ct) * 16 + lq;
        float bv = bias ? bias[col] : 0.f;
        float v[4];
        #pragma unroll
        for (int r = 0; r < 4; ++r) {
            v[r] = acc[ct][r] + bv;
            if (flags & 2) v[r] = 0.5f * v[r] * (1.f + erff(v[r] * 0.70710678118654752f));
            if (flags & 8) v[r] *= SCLOG2;
        }
        if (flags & 4) {
            bf16x4 res = {bf16rne(v[0]), bf16rne(v[1]), bf16rne(v[2]), bf16rne(v[3])};
            *(bf16x4*)((short*)outp + (size_t)col * M + row0 + g * 4) = res;
        } else if (flags & 16) {
            #pragma unroll
            for (int r = 0; r < 4; ++r)
                ((short*)outp)[((size_t)(col >> 4) * M + (row0 + g * 4 + r)) * 16 + (col & 15)] = bf16rne(v[r]);
        } else if (flags & 1) {
            #pragma unroll
            for (int r = 0; r < 4; ++r)
                ((short*)outp)[(size_t)(row0 + g * 4 + r) * N + col] = bf16rne(v[r]);
        } else {
            #pragma unroll
            for (int r = 0; r < 4; ++r)
                ((float*)outp)[(size_t)(row0 + g * 4 + r) * N + col] = v[r];
        }
    }
}

// fused QKV (layer 0): z=0 Q (bf16, *SCLOG2), z=1 K head-major, z=2 V^T
__global__ __launch_bounds__(256) void mfma_gemm3(
        const short* __restrict__ A,
        const short* __restrict__ W0, const short* __restrict__ W1,
        const short* __restrict__ W2,
        short* __restrict__ o0, short* __restrict__ o1, short* __restrict__ o2,
        int M, int K, int N) {
    const short* Wt = (blockIdx.z == 0) ? W0 : (blockIdx.z == 1) ? W1 : W2;
    short* o = (blockIdx.z == 0) ? o0 : (blockIdx.z == 1) ? o1 : o2;
    int flags = (blockIdx.z == 0) ? (1 | 8) : (blockIdx.z == 1) ? 16 : 4;
    gemm_body(A, Wt, nullptr, o, M, K, N, flags, blockIdx.x * 16, 0);
}

// ---------------------------------------------------------------------------
// helpers shared by the two fused cmb kernels
__device__ __forceinline__ void combine_stage(
        const short* __restrict__ pob, const float* __restrict__ pl,
        short (*Al)[136], int row0, int tid) {
    int r = tid >> 4, c0 = (tid & 15) * 8;
    int row = row0 + r;
    int h = c0 >> 4;
    float a8[8] = {0.f,0.f,0.f,0.f,0.f,0.f,0.f,0.f};
    float den = 0.f;
    #pragma unroll
    for (int zz = 0; zz < KSPLIT; ++zz) {
        short8 t = *(const short8*)(pob + (size_t)zz * LL * CC + (size_t)row * CC + c0);
        #pragma unroll
        for (int j = 0; j < 8; ++j) a8[j] += bf16tof(t[j]);
        den += pl[(zz * 8 + h) * LL + row];
    }
    float inv = 1.f / den;
    short8 packed;
    #pragma unroll
    for (int j = 0; j < 8; ++j) packed[j] = bf16rne(a8[j] * inv);
    *(short8*)&Al[r][c0] = packed;
}

__device__ __forceinline__ void w_stage(const short* __restrict__ Wt, int ldw,
                                        int koff, short (*Wl)[136], int tid) {
    int c = (tid & 15) * 8;
    int nb = tid >> 4;
    #pragma unroll
    for (int i = 0; i < 8; ++i) {
        int n = nb + i * 16;
        *(short8*)&Wl[n][c] = *(const short8*)(Wt + (size_t)n * ldw + koff + c);
    }
}

__device__ __forceinline__ void tile_mfma(const bf16x4 af[8], short (*Wl)[136],
                                          f32x4 acc[2], int w, int lq, int g) {
    #pragma unroll
    for (int ct = 0; ct < 2; ++ct) {
        int n = (w * 2 + ct) * 16 + lq;
        #pragma unroll
        for (int ks = 0; ks < 8; ++ks) {
            bf16x4 bfr = *(const bf16x4*)&Wl[n][ks * 16 + g * 4];
            acc[ct] = __builtin_amdgcn_mfma_f32_16x16x16bf16_1k(af[ks], bfr, acc[ct], 0, 0, 0);
        }
    }
}

__device__ __forceinline__ void ln_compute(
        float v[2][4], float y[2][4], const float* __restrict__ gam,
        const float* __restrict__ bet, float (*sL)[4][4], float (*s2L)[4][4],
        int w, int lq, int g, const int cols[2]) {
    float sr[4], s2r[4];
    #pragma unroll
    for (int r = 0; r < 4; ++r) {
        sr[r]  = v[0][r] + v[1][r];
        s2r[r] = v[0][r] * v[0][r] + v[1][r] * v[1][r];
    }
    #pragma unroll
    for (int off = 1; off < 16; off <<= 1) {
        #pragma unroll
        for (int r = 0; r < 4; ++r) {
            sr[r]  += __shfl_xor(sr[r],  off);
            s2r[r] += __shfl_xor(s2r[r], off);
        }
    }
    if (lq == 0) {
        #pragma unroll
        for (int r = 0; r < 4; ++r) { sL[w][g][r] = sr[r]; s2L[w][g][r] = s2r[r]; }
    }
    __syncthreads();
    #pragma unroll
    for (int r = 0; r < 4; ++r) {
        float s = 0.f, s2 = 0.f;
        #pragma unroll
        for (int ww = 0; ww < 4; ++ww) { s += sL[ww][g][r]; s2 += s2L[ww][g][r]; }
        float mu = s * (1.f / CC);
        float var = s2 * (1.f / CC) - mu * mu;
        float rstd = rsqrtf(var + 1e-5f);
        #pragma unroll
        for (int ct = 0; ct < 2; ++ct)
            y[ct][r] = (v[ct][r] - mu) * rstd * gam[cols[ct]] + bet[cols[ct]];
    }
}

// ---------------------------------------------------------------------------
// Layer-l proj+LN (with combine) fused with layer-(l+1) QKV GEMMs.
__global__ __launch_bounds__(256) void mfma_cmb_ln_qkv(
        const short* __restrict__ pob, const float* __restrict__ pl,
        const short* __restrict__ Wpt, const float* __restrict__ resid,
        const float* __restrict__ gam, const float* __restrict__ bet,
        float* __restrict__ outf,
        const short* __restrict__ Wqt, const short* __restrict__ Wkt,
        const short* __restrict__ Wvt,
        short* __restrict__ Qb, short* __restrict__ Kh, short* __restrict__ Vt) {
    __shared__ short Al[16][136];
    __shared__ short Wl[128][136];
    __shared__ float sL[4][4][4], s2L[4][4][4];
    const int tid = threadIdx.x;
    const int lane = tid & 63;
    const int w = tid >> 6;
    const int lq = lane & 15, g = lane >> 4;
    const int row0 = blockIdx.x * 16;

    combine_stage(pob, pl, Al, row0, tid);
    w_stage(Wpt, CC, 0, Wl, tid);
    __syncthreads();

    bf16x4 af[8];
    #pragma unroll
    for (int ks = 0; ks < 8; ++ks)
        af[ks] = *(const bf16x4*)&Al[lq][ks * 16 + g * 4];
    f32x4 acc[2] = {{0.f,0.f,0.f,0.f},{0.f,0.f,0.f,0.f}};
    tile_mfma(af, Wl, acc, w, lq, g);

    float v[2][4], y[2][4];
    int cols[2] = {(w * 2) * 16 + lq, (w * 2 + 1) * 16 + lq};
    #pragma unroll
    for (int ct = 0; ct < 2; ++ct)
        #pragma unroll
        for (int r = 0; r < 4; ++r)
            v[ct][r] = acc[ct][r] + resid[(size_t)(row0 + g * 4 + r) * CC + cols[ct]];
    ln_compute(v, y, gam, bet, sL, s2L, w, lq, g, cols);

    #pragma unroll
    for (int ct = 0; ct < 2; ++ct)
        #pragma unroll
        for (int r = 0; r < 4; ++r) {
            outf[(size_t)(row0 + g * 4 + r) * CC + cols[ct]] = y[ct][r];
            Al[g * 4 + r][cols[ct]] = bf16rne(y[ct][r]);
        }
    __syncthreads();

    bf16x4 af2[8];
    #pragma unroll
    for (int ks = 0; ks < 8; ++ks)
        af2[ks] = *(const bf16x4*)&Al[lq][ks * 16 + g * 4];

    // Q
    __syncthreads();
    w_stage(Wqt, CC, 0, Wl, tid);
    __syncthreads();
    {
        f32x4 aq[2] = {{0.f,0.f,0.f,0.f},{0.f,0.f,0.f,0.f}};
        tile_mfma(af2, Wl, aq, w, lq, g);
        #pragma unroll
        for (int ct = 0; ct < 2; ++ct)
            #pragma unroll
            for (int r = 0; r < 4; ++r)
                Qb[(size_t)(row0 + g * 4 + r) * CC + cols[ct]] = bf16rne(aq[ct][r] * SCLOG2);
    }
    // K (head-major [H][L][16])
    __syncthreads();
    w_stage(Wkt, CC, 0, Wl, tid);
    __syncthreads();
    {
        f32x4 ak[2] = {{0.f,0.f,0.f,0.f},{0.f,0.f,0.f,0.f}};
        tile_mfma(af2, Wl, ak, w, lq, g);
        #pragma unroll
        for (int ct = 0; ct < 2; ++ct)
            #pragma unroll
            for (int r = 0; r < 4; ++r)
                Kh[((size_t)(cols[ct] >> 4) * LL + (row0 + g * 4 + r)) * 16 + (cols[ct] & 15)] = bf16rne(ak[ct][r]);
    }
    // V (transposed [C][L])
    __syncthreads();
    w_stage(Wvt, CC, 0, Wl, tid);
    __syncthreads();
    {
        f32x4 av[2] = {{0.f,0.f,0.f,0.f},{0.f,0.f,0.f,0.f}};
        tile_mfma(af2, Wl, av, w, lq, g);
        #pragma unroll
        for (int ct = 0; ct < 2; ++ct) {
            bf16x4 res = {bf16rne(av[ct][0]), bf16rne(av[ct][1]),
                          bf16rne(av[ct][2]), bf16rne(av[ct][3])};
            *(bf16x4*)(Vt + (size_t)cols[ct] * LL + row0 + g * 4) = res;
        }
    }
}

// ---------------------------------------------------------------------------
// Layer-1 proj+LN (with combine) fused with FFN1+GELU+FFN2+LN2 AND detokenize.
__global__ __launch_bounds__(256) void mfma_cmb_ln_ffn(
        const short* __restrict__ pob, const float* __restrict__ pl,
        const short* __restrict__ Wpt, const float* __restrict__ resid,
        const float* __restrict__ g1, const float* __restrict__ be1,
        const short* __restrict__ w1t, const float* __restrict__ b1,
        const short* __restrict__ w2t, const float* __restrict__ b2,
        const float* __restrict__ g2, const float* __restrict__ be2,
        float* __restrict__ out) {
    __shared__ short Al[16][136];
    __shared__ short Wl[128][136];
    __shared__ short Hl[16][520];
    __shared__ float sL[4][4][4], s2L[4][4][4];
    const int tid = threadIdx.x;
    const int lane = tid & 63;
    const int w = tid >> 6;
    const int lq = lane & 15, g = lane >> 4;
    const int row0 = blockIdx.x * 16;

    combine_stage(pob, pl, Al, row0, tid);
    w_stage(Wpt, CC, 0, Wl, tid);
    __syncthreads();

    bf16x4 af[8];
    #pragma unroll
    for (int ks = 0; ks < 8; ++ks)
        af[ks] = *(const bf16x4*)&Al[lq][ks * 16 + g * 4];
    f32x4 acc[2] = {{0.f,0.f,0.f,0.f},{0.f,0.f,0.f,0.f}};
    tile_mfma(af, Wl, acc, w, lq, g);

    float v[2][4], y[2][4];
    int cols[2] = {(w * 2) * 16 + lq, (w * 2 + 1) * 16 + lq};
    #pragma unroll
    for (int ct = 0; ct < 2; ++ct)
        #pragma unroll
        for (int r = 0; r < 4; ++r)
            v[ct][r] = acc[ct][r] + resid[(size_t)(row0 + g * 4 + r) * CC + cols[ct]];
    ln_compute(v, y, g1, be1, sL, s2L, w, lq, g, cols);

    #pragma unroll
    for (int ct = 0; ct < 2; ++ct)
        #pragma unroll
        for (int r = 0; r < 4; ++r)
            Al[g * 4 + r][cols[ct]] = bf16rne(y[ct][r]);
    __syncthreads();

    bf16x4 af2[8];
    #pragma unroll
    for (int ks = 0; ks < 8; ++ks)
        af2[ks] = *(const bf16x4*)&Al[lq][ks * 16 + g * 4];

    // ---- FFN1: 4 column chunks of 128 ----
    for (int cc = 0; cc < 4; ++cc) {
        __syncthreads();
        w_stage(w1t + (size_t)cc * 128 * CC, CC, 0, Wl, tid);
        __syncthreads();
        f32x4 a1[2] = {{0.f,0.f,0.f,0.f},{0.f,0.f,0.f,0.f}};
        tile_mfma(af2, Wl, a1, w, lq, g);
        #pragma unroll
        for (int ct = 0; ct < 2; ++ct) {
            int col = (w * 2 + ct) * 16 + lq;
            float bv = b1[cc * 128 + col];
            #pragma unroll
            for (int r = 0; r < 4; ++r) {
                float vv = a1[ct][r] + bv;
                vv = 0.5f * vv * (1.f + erff(vv * 0.70710678118654752f));
                Hl[g * 4 + r][cc * 128 + col] = bf16rne(vv);
            }
        }
    }
    __syncthreads();

    // ---- FFN2: K=512 in 4 chunks ----
    f32x4 acc2[2] = {{0.f,0.f,0.f,0.f},{0.f,0.f,0.f,0.f}};
    for (int kc = 0; kc < 4; ++kc) {
        w_stage(w2t, 512, kc * 128, Wl, tid);
        __syncthreads();
        bf16x4 hf[8];
        #pragma unroll
        for (int ks = 0; ks < 8; ++ks)
            hf[ks] = *(const bf16x4*)&Hl[lq][kc * 128 + ks * 16 + g * 4];
        tile_mfma(hf, Wl, acc2, w, lq, g);
        __syncthreads();
    }

    // ---- bias + residual(y in regs) + LN2 -> direct detokenized output ----
    float v2[2][4], y2[2][4];
    #pragma unroll
    for (int ct = 0; ct < 2; ++ct) {
        float bv = b2[cols[ct]];
        #pragma unroll
        for (int r = 0; r < 4; ++r)
            v2[ct][r] = acc2[ct][r] + bv + y[ct][r];
    }
    ln_compute(v2, y2, g2, be2, sL, s2L, w, lq, g, cols);
    {
        int rowb = row0 + g * 4;            // 4 consecutive token rows
        int s  = rowb / NN;
        int n0 = rowb - s * NN;             // n0 % 4 == 0 (1000 % 4 == 0)
        #pragma unroll
        for (int ct = 0; ct < 2; ++ct) {
            f32x4 res = {y2[ct][0], y2[ct][1], y2[ct][2], y2[ct][3]};
            *(f32x4*)(out + ((size_t)s * CC + cols[ct]) * NN + n0) = res;
        }
    }
}

// ---------------------------------------------------------------------------
// MFMA flash attention (r16 staging + depth-3 prefetch, 4 q-tiles per wave):
// fixed-shift softmax, sequence-aligned split-K. Blocks per (h,z) halve ->
// K/V fetch traffic halves; per-tile compute doubles, covering latency.
__global__ __launch_bounds__(256) void attn_mfma_kernel(
        const short* __restrict__ Qb, const short* __restrict__ Kh,
        const short* __restrict__ Vt, const float* __restrict__ kbw,
        short* __restrict__ pob, float* __restrict__ pl) {
    __shared__ short Kl[2][32][KROW];
    __shared__ short Vl[2][16][VROW];
    const int tid  = threadIdx.x;
    const int lane = tid & 63;
    const int wv   = tid >> 6;
    const int lq = lane & 15;
    const int g  = lane >> 4;
    const int h  = blockIdx.y;
    const int z  = blockIdx.z;
    const int qt0 = blockIdx.x * 16 + wv * 4;
    const int hd0 = h * 16;
    const int kbase = z * NN;

    bf16x4 qf[4];
    bool qv[4];
    #pragma unroll
    for (int qi = 0; qi < 4; ++qi) {
        int qt = qt0 + qi;
        qv[qi] = qt < LL / 16;
        qf[qi] = (bf16x4){0, 0, 0, 0};
        if (qv[qi])
            qf[qi] = *(const bf16x4*)(Qb + (size_t)(qt * 16 + lq) * CC + hd0 + 4 * g);
    }

    const short onev = (lq == 0) ? (short)0x3F80 : (short)0;
    const bf16x4 af1 = {onev, onev, onev, onev};

    const short* kgp = Kh + ((size_t)h * LL + kbase) * 16 + tid * 2;
    const short* vgp = Vt + (size_t)(hd0 + (tid >> 4)) * LL + kbase + (tid & 15) * 2;
    short* kwp = &Kl[0][0][0] + (tid >> 3) * KROW + (tid & 7) * 2;
    short* vwp = &Vl[0][0][0] + (tid >> 4) * VROW + (tid & 15) * 2;
    const int kbufstride = 32 * KROW;
    const int vbufstride = 16 * VROW;

    f32x4 o[4]  = {{0.f,0.f,0.f,0.f},{0.f,0.f,0.f,0.f},
                   {0.f,0.f,0.f,0.f},{0.f,0.f,0.f,0.f}};
    f32x4 ps[4] = {{0.f,0.f,0.f,0.f},{0.f,0.f,0.f,0.f},
                   {0.f,0.f,0.f,0.f},{0.f,0.f,0.f,0.f}};

    {   // prologue: stage tile 0 into buf 0; issue tiles 1,2 loads
        unsigned kd = *(const unsigned*)kgp;
        unsigned vd = *(const unsigned*)vgp;
        *(unsigned*)kwp = kd;
        *(unsigned*)vwp = vd;
    }
    unsigned kd1 = *(const unsigned*)(kgp + (size_t)1 * 32 * 16);
    unsigned vd1 = *(const unsigned*)(vgp + 1 * 32);
    unsigned kd2 = *(const unsigned*)(kgp + (size_t)2 * 32 * 16);
    unsigned vd2 = *(const unsigned*)(vgp + 2 * 32);
    __syncthreads();

    for (int t = 0; t < 31; ++t) {
        unsigned kd3, vd3;
        if (t < 29) {
            kd3 = *(const unsigned*)(kgp + (size_t)(t + 3) * 32 * 16);
            vd3 = *(const unsigned*)(vgp + (t + 3) * 32);
        }
        {
            const short* kb = &Kl[t & 1][0][0];
            const short* vb = &Vl[t & 1][0][0];
            bf16x4 K0 = *(const bf16x4*)(kb + lq * KROW + 4 * g);
            bf16x4 K1 = *(const bf16x4*)(kb + (16 + lq) * KROW + 4 * g);
            bf16x4 V0 = *(const bf16x4*)(vb + lq * VROW + 4 * g);
            bf16x4 V1 = *(const bf16x4*)(vb + lq * VROW + 16 + 4 * g);
            const f32x4 zz = {0.f, 0.f, 0.f, 0.f};
            #pragma unroll
            for (int qi = 0; qi < 4; ++qi) {
                f32x4 s0 = __builtin_amdgcn_mfma_f32_16x16x16bf16_1k(K0, qf[qi], zz, 0, 0, 0);
                f32x4 s1 = __builtin_amdgcn_mfma_f32_16x16x16bf16_1k(K1, qf[qi], zz, 0, 0, 0);
                float p0[4], p1[4];
                #pragma unroll
                for (int r = 0; r < 4; ++r) {
                    p0[r] = __builtin_amdgcn_exp2f(s0[r]);
                    p1[r] = __builtin_amdgcn_exp2f(s1[r]);
                }
                bf16x4 pt0 = pack4(p0), pt1 = pack4(p1);
                o[qi]  = __builtin_amdgcn_mfma_f32_16x16x16bf16_1k(V0, pt0, o[qi], 0, 0, 0);
                o[qi]  = __builtin_amdgcn_mfma_f32_16x16x16bf16_1k(V1, pt1, o[qi], 0, 0, 0);
                ps[qi] = __builtin_amdgcn_mfma_f32_16x16x16bf16_1k(af1, pt0, ps[qi], 0, 0, 0);
                ps[qi] = __builtin_amdgcn_mfma_f32_16x16x16bf16_1k(af1, pt1, ps[qi], 0, 0, 0);
            }
        }
        const int nb = (t + 1) & 1;
        *(unsigned*)(kwp + nb * kbufstride) = kd1;
        *(unsigned*)(vwp + nb * vbufstride) = vd1;
        __syncthreads();
        kd1 = kd2; vd1 = vd2;
        if (t < 29) { kd2 = kd3; vd2 = vd3; }
    }

    {   // tail tile 31: local keys 992..999 valid; mask P (g>=2) AND V-frag
        const short* kb = &Kl[1][0][0];
        const short* vb = &Vl[1][0][0];
        bf16x4 K0 = *(const bf16x4*)(kb + lq * KROW + 4 * g);
        bf16x4 V0 = *(const bf16x4*)(vb + lq * VROW + 4 * g);
        if (g >= 2) V0 = (bf16x4){0, 0, 0, 0};
        const f32x4 zz = {0.f, 0.f, 0.f, 0.f};
        #pragma unroll
        for (int qi = 0; qi < 4; ++qi) {
            f32x4 s0 = __builtin_amdgcn_mfma_f32_16x16x16bf16_1k(K0, qf[qi], zz, 0, 0, 0);
            float p0[4];
            #pragma unroll
            for (int r = 0; r < 4; ++r)
                p0[r] = (g < 2) ? __builtin_amdgcn_exp2f(s0[r]) : 0.f;
            bf16x4 pt0 = pack4(p0);
            o[qi]  = __builtin_amdgcn_mfma_f32_16x16x16bf16_1k(V0, pt0, o[qi], 0, 0, 0);
            ps[qi] = __builtin_amdgcn_mfma_f32_16x16x16bf16_1k(af1, pt0, ps[qi], 0, 0, 0);
        }
    }

    const float wz = kbw[z];
    #pragma unroll
    for (int qi = 0; qi < 4; ++qi) {
        if (qv[qi]) {
            int qt = qt0 + qi;
            bf16x4 ow = {bf16rne(o[qi][0] * wz), bf16rne(o[qi][1] * wz),
                         bf16rne(o[qi][2] * wz), bf16rne(o[qi][3] * wz)};
            *(bf16x4*)(pob + (size_t)z * LL * CC + (size_t)(qt * 16 + lq) * CC + hd0 + 4 * g) = ow;
            if (g == 0) pl[(z * 8 + h) * LL + qt * 16 + lq] = ps[qi][0] * wz;
        }
    }
}

// ---------------------------------------------------------------------------
extern "C" void kernel_launch(void* const* d_in, const int* in_sizes, int n_in,
                              void* d_out, int out_size, void* d_ws, size_t ws_size,
                              hipStream_t stream) {
    const float* z    = (const float*)d_in[0];
    const float* r    = (const float*)d_in[1];
    const float* se   = (const float*)d_in[2];
    const float* Wq   = (const float*)d_in[3];
    const float* Wk   = (const float*)d_in[4];
    const float* Wv   = (const float*)d_in[5];
    const float* Wp   = (const float*)d_in[6];
    const float* beta = (const float*)d_in[7];
    const float* ln1g = (const float*)d_in[8];
    const float* ln1b = (const float*)d_in[9];
    const float* w1   = (const float*)d_in[10];
    const float* b1   = (const float*)d_in[11];
    const float* w2   = (const float*)d_in[12];
    const float* b2   = (const float*)d_in[13];
    const float* ln2g = (const float*)d_in[14];
    const float* ln2b = (const float*)d_in[15];
    float* out = (float*)d_out;

    float* ws   = (float*)d_ws;
    float* tok  = ws;                               // 512000 f
    float* kbw  = tok + LL * CC;                    // 8 f (16B aligned)
    float* pl   = kbw + 8;                          // KSPLIT*8*LL = 128000 f
    short* pob  = (short*)(pl + KSPLIT * 8 * LL);   // KSPLIT*LL*CC sh = 4 MB
    short* tokb = pob + (size_t)KSPLIT * LL * CC;
    short* Qb   = tokb + LL * CC;
    short* Kh   = Qb   + LL * CC;                   // head-major [H][L][16] + slack
    short* Vt   = Kh   + LL * CC + 1024;            // transposed [C][L] + slack
    short* wt8  = Vt   + LL * CC + 1024;
    short* w1t  = wt8  + 8 * 16384;
    short* w2t  = w1t  + 65536;

    const short* wq0 = wt8 + (size_t)0 * 16384;
    const short* wq1 = wt8 + (size_t)1 * 16384;
    const short* wk0 = wt8 + (size_t)2 * 16384;
    const short* wk1 = wt8 + (size_t)3 * 16384;
    const short* wv0 = wt8 + (size_t)4 * 16384;
    const short* wv1 = wt8 + (size_t)5 * 16384;
    const short* wp0 = wt8 + (size_t)6 * 16384;
    const short* wp1 = wt8 + (size_t)7 * 16384;

    prep_tok_kernel<<<769, 256, 0, stream>>>(Wq, Wk, Wv, Wp, w1, w2, r, beta,
                                             wt8, w1t, w2t, kbw, z, se, tok, tokb);

    // layer 0 QKV
    mfma_gemm3<<<dim3(LL / 16, 1, 3), 256, 0, stream>>>(
        tokb, wq0, wk0, wv0, Qb, Kh, Vt, LL, CC, CC);
    // layer 0 attention (4 q-tiles/wave: 16 q-tiles per block)
    attn_mfma_kernel<<<dim3((LL / 16 + 15) / 16, 8, KSPLIT), 256, 0, stream>>>(
        Qb, Kh, Vt, kbw + 0 * KSPLIT, pob, pl);
    // layer 0 proj+LN fused with layer 1 QKV
    mfma_cmb_ln_qkv<<<LL / 16, 256, 0, stream>>>(
        pob, pl, wp0, tok, ln1g + 0 * CC, ln1b + 0 * CC, tok,
        wq1, wk1, wv1, Qb, Kh, Vt);
    // layer 1 attention
    attn_mfma_kernel<<<dim3((LL / 16 + 15) / 16, 8, KSPLIT), 256, 0, stream>>>(
        Qb, Kh, Vt, kbw + 1 * KSPLIT, pob, pl);
    // layer 1 proj+LN fused with FFN + LN2 + detokenize (writes d_out directly)
    mfma_cmb_ln_ffn<<<LL / 16, 256, 0, stream>>>(
        pob, pl, wp1, tok, ln1g + 1 * CC, ln1b + 1 * CC,
        w1t, b1, w2t, b2, ln2g, ln2b, out);
}

// Round 20
// 87.293 us; speedup vs baseline: 1.0980x; 1.0980x over previous
//
#include <hip/hip_runtime.h>
#include <hip/hip_bf16.h>
#include <math.h>

// Problem constants: S=4, B=1, C=128, h=w=d=10 -> N=1000, L=4000, nL=2, H=8, Dh=16
#define LL 4000
#define CC 128
#define NN 1000
#define NLAYER 2
#define KSPLIT 4                        // == S; split-K aligned to sequences
#define SCLOG2 0.36067376022224085f    // 0.25 * log2(e), folded into Q
#define KROW 20                        // padded LDS row (shorts) for K tile [32][KROW]
#define VROW 36                        // padded LDS row (shorts) for V^T tile [16][VROW]

typedef __attribute__((ext_vector_type(4))) short bf16x4;
typedef __attribute__((ext_vector_type(8))) short short8;
typedef __attribute__((ext_vector_type(4))) float f32x4;
typedef __attribute__((ext_vector_type(2))) unsigned int u32x2;

__device__ __forceinline__ short bf16rne(float f) {
    return __builtin_bit_cast(short, __float2bfloat16(f));
}
__device__ __forceinline__ float bf16tof(short s) {
    return __builtin_bit_cast(float, (unsigned)((unsigned short)s) << 16);
}

// pack 4 f32 -> 4 bf16 (truncate) via 2x v_perm_b32
__device__ __forceinline__ bf16x4 pack4(const float* p) {
    unsigned w01 = __builtin_amdgcn_perm(__builtin_bit_cast(unsigned, p[1]),
                                         __builtin_bit_cast(unsigned, p[0]),
                                         0x07060302u);
    unsigned w23 = __builtin_amdgcn_perm(__builtin_bit_cast(unsigned, p[3]),
                                         __builtin_bit_cast(unsigned, p[2]),
                                         0x07060302u);
    u32x2 w = {w01, w23};
    return __builtin_bit_cast(bf16x4, w);
}

// ---------------------------------------------------------------------------
// merged preamble: weight prep (blocks 0..1024) + tokenize (blocks 1025..1536)
__global__ void prep_tok_kernel(const float* __restrict__ Wq, const float* __restrict__ Wk,
                                const float* __restrict__ Wv, const float* __restrict__ Wp,
                                const float* __restrict__ w1, const float* __restrict__ w2,
                                const float* __restrict__ r, const float* __restrict__ beta,
                                short* __restrict__ wt8, short* __restrict__ w1t,
                                short* __restrict__ w2t, float* __restrict__ kbw,
                                const float* __restrict__ z, const float* __restrict__ se,
                                float* __restrict__ tok, short* __restrict__ tokb) {
    __shared__ float tl[32][33];
    const int bid = blockIdx.x;
    if (bid < 1025) {
        int idx = bid * 256 + threadIdx.x;
        if (idx < 8 * 16384) {
            int m = idx >> 14, i = idx & 16383;
            int n = i >> 7, k = i & 127;
            const float* src = (m < 2) ? Wq + (size_t)m * 16384
                             : (m < 4) ? Wk + (size_t)(m - 2) * 16384
                             : (m < 6) ? Wv + (size_t)(m - 4) * 16384
                                       : Wp + (size_t)(m - 6) * 16384;
            wt8[idx] = bf16rne(src[k * 128 + n]);
        } else if (idx < 8 * 16384 + 65536) {
            int i = idx - 8 * 16384;
            int n = i >> 7, k = i & 127;
            w1t[i] = bf16rne(w1[(size_t)k * 512 + n]);
        } else if (idx < 8 * 16384 + 2 * 65536) {
            int i = idx - 8 * 16384 - 65536;
            int n = i >> 9, k = i & 511;
            w2t[i] = bf16rne(w2[(size_t)k * 128 + n]);
        } else if (idx < 8 * 16384 + 2 * 65536 + NLAYER * KSPLIT) {
            int i = idx - (8 * 16384 + 2 * 65536);
            int l = i / KSPLIT, zz = i - l * KSPLIT;
            kbw[i] = exp2f(beta[l] * __log2f(r[zz]));
        }
    } else {
        int b2 = bid - 1025;
        const int n0 = (b2 & 31) * 32;
        const int c0 = ((b2 >> 5) & 3) * 32;
        const int s  = b2 >> 7;
        const int tx = threadIdx.x & 31, ty = threadIdx.x >> 5;
        #pragma unroll
        for (int i = 0; i < 4; ++i) {
            int n = n0 + tx;
            if (n < NN) tl[ty * 4 + i][tx] = z[((size_t)s * CC + c0 + ty * 4 + i) * NN + n];
        }
        __syncthreads();
        #pragma unroll
        for (int i = 0; i < 4; ++i) {
            int n = n0 + ty * 4 + i;
            if (n < NN) {
                int c = c0 + tx;
                float v = tl[tx][ty * 4 + i] + se[s * CC + c];
                size_t o = ((size_t)(s * NN + n)) * CC + c;
                tok[o] = v;
                tokb[o] = bf16rne(v);
            }
        }
    }
}

// ---------------------------------------------------------------------------
// MFMA GEMM body (16-row tile): out[M,N] = act(A@Wt^T + bias)
// flags: 1 = bf16 out, 2 = exact GELU, 4 = bf16 transposed out [N][M],
//        8 = *SCLOG2, 16 = bf16 head-major out [N/16][M][16]
__device__ __forceinline__ void gemm_body(
        const short* __restrict__ A, const short* __restrict__ Wt,
        const float* __restrict__ bias, void* __restrict__ outp,
        int M, int K, int N, int flags, int row0, int col0) {
    __shared__ short Al[16][136];
    __shared__ short Wl[128][136];
    const int tid = threadIdx.x;
    const int lane = tid & 63;
    const int w = tid >> 6;
    const int lq = lane & 15, g = lane >> 4;

    f32x4 acc[2] = {{0.f,0.f,0.f,0.f},{0.f,0.f,0.f,0.f}};

    for (int kc = 0; kc < K; kc += 128) {
        {
            int r = tid >> 4, c = (tid & 15) * 8;
            *(short8*)&Al[r][c] = *(const short8*)(A + (size_t)(row0 + r) * K + kc + c);
        }
        {
            int c = (tid & 15) * 8;
            int nb = tid >> 4;
            #pragma unroll
            for (int i = 0; i < 8; ++i) {
                int n = nb + i * 16;
                *(short8*)&Wl[n][c] = *(const short8*)(Wt + (size_t)(col0 + n) * K + kc + c);
            }
        }
        __syncthreads();
        bf16x4 af[8];
        #pragma unroll
        for (int ks = 0; ks < 8; ++ks)
            af[ks] = *(const bf16x4*)&Al[lq][ks * 16 + g * 4];
        #pragma unroll
        for (int ct = 0; ct < 2; ++ct) {
            int n = (w * 2 + ct) * 16 + lq;
            #pragma unroll
            for (int ks = 0; ks < 8; ++ks) {
                bf16x4 bfr = *(const bf16x4*)&Wl[n][ks * 16 + g * 4];
                acc[ct] = __builtin_amdgcn_mfma_f32_16x16x16bf16_1k(af[ks], bfr, acc[ct], 0, 0, 0);
            }
        }
        __syncthreads();
    }
    #pragma unroll
    for (int ct = 0; ct < 2; ++ct) {
        int col = col0 + (w * 2 + ct) * 16 + lq;
        float bv = bias ? bias[col] : 0.f;
        float v[4];
        #pragma unroll
        for (int r = 0; r < 4; ++r) {
            v[r] = acc[ct][r] + bv;
            if (flags & 2) v[r] = 0.5f * v[r] * (1.f + erff(v[r] * 0.70710678118654752f));
            if (flags & 8) v[r] *= SCLOG2;
        }
        if (flags & 4) {
            bf16x4 res = {bf16rne(v[0]), bf16rne(v[1]), bf16rne(v[2]), bf16rne(v[3])};
            *(bf16x4*)((short*)outp + (size_t)col * M + row0 + g * 4) = res;
        } else if (flags & 16) {
            #pragma unroll
            for (int r = 0; r < 4; ++r)
                ((short*)outp)[((size_t)(col >> 4) * M + (row0 + g * 4 + r)) * 16 + (col & 15)] = bf16rne(v[r]);
        } else if (flags & 1) {
            #pragma unroll
            for (int r = 0; r < 4; ++r)
                ((short*)outp)[(size_t)(row0 + g * 4 + r) * N + col] = bf16rne(v[r]);
        } else {
            #pragma unroll
            for (int r = 0; r < 4; ++r)
                ((float*)outp)[(size_t)(row0 + g * 4 + r) * N + col] = v[r];
        }
    }
}

// fused QKV (layer 0): z=0 Q (bf16, *SCLOG2), z=1 K head-major, z=2 V^T
__global__ __launch_bounds__(256) void mfma_gemm3(
        const short* __restrict__ A,
        const short* __restrict__ W0, const short* __restrict__ W1,
        const short* __restrict__ W2,
        short* __restrict__ o0, short* __restrict__ o1, short* __restrict__ o2,
        int M, int K, int N) {
    const short* Wt = (blockIdx.z == 0) ? W0 : (blockIdx.z == 1) ? W1 : W2;
    short* o = (blockIdx.z == 0) ? o0 : (blockIdx.z == 1) ? o1 : o2;
    int flags = (blockIdx.z == 0) ? (1 | 8) : (blockIdx.z == 1) ? 16 : 4;
    gemm_body(A, Wt, nullptr, o, M, K, N, flags, blockIdx.x * 16, 0);
}

// ---------------------------------------------------------------------------
// helpers shared by the two fused cmb kernels
__device__ __forceinline__ void combine_stage(
        const short* __restrict__ pob, const float* __restrict__ pl,
        short (*Al)[136], int row0, int tid) {
    int r = tid >> 4, c0 = (tid & 15) * 8;
    int row = row0 + r;
    int h = c0 >> 4;
    float a8[8] = {0.f,0.f,0.f,0.f,0.f,0.f,0.f,0.f};
    float den = 0.f;
    #pragma unroll
    for (int zz = 0; zz < KSPLIT; ++zz) {
        short8 t = *(const short8*)(pob + (size_t)zz * LL * CC + (size_t)row * CC + c0);
        #pragma unroll
        for (int j = 0; j < 8; ++j) a8[j] += bf16tof(t[j]);
        den += pl[(zz * 8 + h) * LL + row];
    }
    float inv = 1.f / den;
    short8 packed;
    #pragma unroll
    for (int j = 0; j < 8; ++j) packed[j] = bf16rne(a8[j] * inv);
    *(short8*)&Al[r][c0] = packed;
}

__device__ __forceinline__ void w_stage(const short* __restrict__ Wt, int ldw,
                                        int koff, short (*Wl)[136], int tid) {
    int c = (tid & 15) * 8;
    int nb = tid >> 4;
    #pragma unroll
    for (int i = 0; i < 8; ++i) {
        int n = nb + i * 16;
        *(short8*)&Wl[n][c] = *(const short8*)(Wt + (size_t)n * ldw + koff + c);
    }
}

__device__ __forceinline__ void tile_mfma(const bf16x4 af[8], short (*Wl)[136],
                                          f32x4 acc[2], int w, int lq, int g) {
    #pragma unroll
    for (int ct = 0; ct < 2; ++ct) {
        int n = (w * 2 + ct) * 16 + lq;
        #pragma unroll
        for (int ks = 0; ks < 8; ++ks) {
            bf16x4 bfr = *(const bf16x4*)&Wl[n][ks * 16 + g * 4];
            acc[ct] = __builtin_amdgcn_mfma_f32_16x16x16bf16_1k(af[ks], bfr, acc[ct], 0, 0, 0);
        }
    }
}

__device__ __forceinline__ void ln_compute(
        float v[2][4], float y[2][4], const float* __restrict__ gam,
        const float* __restrict__ bet, float (*sL)[4][4], float (*s2L)[4][4],
        int w, int lq, int g, const int cols[2]) {
    float sr[4], s2r[4];
    #pragma unroll
    for (int r = 0; r < 4; ++r) {
        sr[r]  = v[0][r] + v[1][r];
        s2r[r] = v[0][r] * v[0][r] + v[1][r] * v[1][r];
    }
    #pragma unroll
    for (int off = 1; off < 16; off <<= 1) {
        #pragma unroll
        for (int r = 0; r < 4; ++r) {
            sr[r]  += __shfl_xor(sr[r],  off);
            s2r[r] += __shfl_xor(s2r[r], off);
        }
    }
    if (lq == 0) {
        #pragma unroll
        for (int r = 0; r < 4; ++r) { sL[w][g][r] = sr[r]; s2L[w][g][r] = s2r[r]; }
    }
    __syncthreads();
    #pragma unroll
    for (int r = 0; r < 4; ++r) {
        float s = 0.f, s2 = 0.f;
        #pragma unroll
        for (int ww = 0; ww < 4; ++ww) { s += sL[ww][g][r]; s2 += s2L[ww][g][r]; }
        float mu = s * (1.f / CC);
        float var = s2 * (1.f / CC) - mu * mu;
        float rstd = rsqrtf(var + 1e-5f);
        #pragma unroll
        for (int ct = 0; ct < 2; ++ct)
            y[ct][r] = (v[ct][r] - mu) * rstd * gam[cols[ct]] + bet[cols[ct]];
    }
}

// ---------------------------------------------------------------------------
// Layer-l proj+LN (with combine) fused with layer-(l+1) QKV GEMMs.
__global__ __launch_bounds__(256) void mfma_cmb_ln_qkv(
        const short* __restrict__ pob, const float* __restrict__ pl,
        const short* __restrict__ Wpt, const float* __restrict__ resid,
        const float* __restrict__ gam, const float* __restrict__ bet,
        float* __restrict__ outf,
        const short* __restrict__ Wqt, const short* __restrict__ Wkt,
        const short* __restrict__ Wvt,
        short* __restrict__ Qb, short* __restrict__ Kh, short* __restrict__ Vt) {
    __shared__ short Al[16][136];
    __shared__ short Wl[128][136];
    __shared__ float sL[4][4][4], s2L[4][4][4];
    const int tid = threadIdx.x;
    const int lane = tid & 63;
    const int w = tid >> 6;
    const int lq = lane & 15, g = lane >> 4;
    const int row0 = blockIdx.x * 16;

    combine_stage(pob, pl, Al, row0, tid);
    w_stage(Wpt, CC, 0, Wl, tid);
    __syncthreads();

    bf16x4 af[8];
    #pragma unroll
    for (int ks = 0; ks < 8; ++ks)
        af[ks] = *(const bf16x4*)&Al[lq][ks * 16 + g * 4];
    f32x4 acc[2] = {{0.f,0.f,0.f,0.f},{0.f,0.f,0.f,0.f}};
    tile_mfma(af, Wl, acc, w, lq, g);

    float v[2][4], y[2][4];
    int cols[2] = {(w * 2) * 16 + lq, (w * 2 + 1) * 16 + lq};
    #pragma unroll
    for (int ct = 0; ct < 2; ++ct)
        #pragma unroll
        for (int r = 0; r < 4; ++r)
            v[ct][r] = acc[ct][r] + resid[(size_t)(row0 + g * 4 + r) * CC + cols[ct]];
    ln_compute(v, y, gam, bet, sL, s2L, w, lq, g, cols);

    #pragma unroll
    for (int ct = 0; ct < 2; ++ct)
        #pragma unroll
        for (int r = 0; r < 4; ++r) {
            outf[(size_t)(row0 + g * 4 + r) * CC + cols[ct]] = y[ct][r];
            Al[g * 4 + r][cols[ct]] = bf16rne(y[ct][r]);
        }
    __syncthreads();

    bf16x4 af2[8];
    #pragma unroll
    for (int ks = 0; ks < 8; ++ks)
        af2[ks] = *(const bf16x4*)&Al[lq][ks * 16 + g * 4];

    // Q
    __syncthreads();
    w_stage(Wqt, CC, 0, Wl, tid);
    __syncthreads();
    {
        f32x4 aq[2] = {{0.f,0.f,0.f,0.f},{0.f,0.f,0.f,0.f}};
        tile_mfma(af2, Wl, aq, w, lq, g);
        #pragma unroll
        for (int ct = 0; ct < 2; ++ct)
            #pragma unroll
            for (int r = 0; r < 4; ++r)
                Qb[(size_t)(row0 + g * 4 + r) * CC + cols[ct]] = bf16rne(aq[ct][r] * SCLOG2);
    }
    // K (head-major [H][L][16])
    __syncthreads();
    w_stage(Wkt, CC, 0, Wl, tid);
    __syncthreads();
    {
        f32x4 ak[2] = {{0.f,0.f,0.f,0.f},{0.f,0.f,0.f,0.f}};
        tile_mfma(af2, Wl, ak, w, lq, g);
        #pragma unroll
        for (int ct = 0; ct < 2; ++ct)
            #pragma unroll
            for (int r = 0; r < 4; ++r)
                Kh[((size_t)(cols[ct] >> 4) * LL + (row0 + g * 4 + r)) * 16 + (cols[ct] & 15)] = bf16rne(ak[ct][r]);
    }
    // V (transposed [C][L])
    __syncthreads();
    w_stage(Wvt, CC, 0, Wl, tid);
    __syncthreads();
    {
        f32x4 av[2] = {{0.f,0.f,0.f,0.f},{0.f,0.f,0.f,0.f}};
        tile_mfma(af2, Wl, av, w, lq, g);
        #pragma unroll
        for (int ct = 0; ct < 2; ++ct) {
            bf16x4 res = {bf16rne(av[ct][0]), bf16rne(av[ct][1]),
                          bf16rne(av[ct][2]), bf16rne(av[ct][3])};
            *(bf16x4*)(Vt + (size_t)cols[ct] * LL + row0 + g * 4) = res;
        }
    }
}

// ---------------------------------------------------------------------------
// Layer-1 proj+LN (with combine) fused with FFN1+GELU+FFN2+LN2 AND the final
// detokenize: each epilogue thread holds 4 consecutive token rows (1000%4==0,
// so no sequence straddle) at one channel -> one aligned f32x4 store to
// out[(s*C+col)*N + n]. No tok write, no detok kernel.
__global__ __launch_bounds__(256) void mfma_cmb_ln_ffn(
        const short* __restrict__ pob, const float* __restrict__ pl,
        const short* __restrict__ Wpt, const float* __restrict__ resid,
        const float* __restrict__ g1, const float* __restrict__ be1,
        const short* __restrict__ w1t, const float* __restrict__ b1,
        const short* __restrict__ w2t, const float* __restrict__ b2,
        const float* __restrict__ g2, const float* __restrict__ be2,
        float* __restrict__ out) {
    __shared__ short Al[16][136];
    __shared__ short Wl[128][136];
    __shared__ short Hl[16][520];
    __shared__ float sL[4][4][4], s2L[4][4][4];
    const int tid = threadIdx.x;
    const int lane = tid & 63;
    const int w = tid >> 6;
    const int lq = lane & 15, g = lane >> 4;
    const int row0 = blockIdx.x * 16;

    combine_stage(pob, pl, Al, row0, tid);
    w_stage(Wpt, CC, 0, Wl, tid);
    __syncthreads();

    bf16x4 af[8];
    #pragma unroll
    for (int ks = 0; ks < 8; ++ks)
        af[ks] = *(const bf16x4*)&Al[lq][ks * 16 + g * 4];
    f32x4 acc[2] = {{0.f,0.f,0.f,0.f},{0.f,0.f,0.f,0.f}};
    tile_mfma(af, Wl, acc, w, lq, g);

    float v[2][4], y[2][4];
    int cols[2] = {(w * 2) * 16 + lq, (w * 2 + 1) * 16 + lq};
    #pragma unroll
    for (int ct = 0; ct < 2; ++ct)
        #pragma unroll
        for (int r = 0; r < 4; ++r)
            v[ct][r] = acc[ct][r] + resid[(size_t)(row0 + g * 4 + r) * CC + cols[ct]];
    ln_compute(v, y, g1, be1, sL, s2L, w, lq, g, cols);

    #pragma unroll
    for (int ct = 0; ct < 2; ++ct)
        #pragma unroll
        for (int r = 0; r < 4; ++r)
            Al[g * 4 + r][cols[ct]] = bf16rne(y[ct][r]);
    __syncthreads();

    bf16x4 af2[8];
    #pragma unroll
    for (int ks = 0; ks < 8; ++ks)
        af2[ks] = *(const bf16x4*)&Al[lq][ks * 16 + g * 4];

    // ---- FFN1: 4 column chunks of 128 ----
    for (int cc = 0; cc < 4; ++cc) {
        __syncthreads();
        w_stage(w1t + (size_t)cc * 128 * CC, CC, 0, Wl, tid);
        __syncthreads();
        f32x4 a1[2] = {{0.f,0.f,0.f,0.f},{0.f,0.f,0.f,0.f}};
        tile_mfma(af2, Wl, a1, w, lq, g);
        #pragma unroll
        for (int ct = 0; ct < 2; ++ct) {
            int col = (w * 2 + ct) * 16 + lq;
            float bv = b1[cc * 128 + col];
            #pragma unroll
            for (int r = 0; r < 4; ++r) {
                float vv = a1[ct][r] + bv;
                vv = 0.5f * vv * (1.f + erff(vv * 0.70710678118654752f));
                Hl[g * 4 + r][cc * 128 + col] = bf16rne(vv);
            }
        }
    }
    __syncthreads();

    // ---- FFN2: K=512 in 4 chunks ----
    f32x4 acc2[2] = {{0.f,0.f,0.f,0.f},{0.f,0.f,0.f,0.f}};
    for (int kc = 0; kc < 4; ++kc) {
        w_stage(w2t, 512, kc * 128, Wl, tid);
        __syncthreads();
        bf16x4 hf[8];
        #pragma unroll
        for (int ks = 0; ks < 8; ++ks)
            hf[ks] = *(const bf16x4*)&Hl[lq][kc * 128 + ks * 16 + g * 4];
        tile_mfma(hf, Wl, acc2, w, lq, g);
        __syncthreads();
    }

    // ---- bias + residual(y in regs) + LN2 -> direct detokenized output ----
    float v2[2][4], y2[2][4];
    #pragma unroll
    for (int ct = 0; ct < 2; ++ct) {
        float bv = b2[cols[ct]];
        #pragma unroll
        for (int r = 0; r < 4; ++r)
            v2[ct][r] = acc2[ct][r] + bv + y[ct][r];
    }
    ln_compute(v2, y2, g2, be2, sL, s2L, w, lq, g, cols);
    {
        int rowb = row0 + g * 4;            // 4 consecutive token rows
        int s  = rowb / NN;
        int n0 = rowb - s * NN;             // n0 % 4 == 0 (1000 % 4 == 0)
        #pragma unroll
        for (int ct = 0; ct < 2; ++ct) {
            f32x4 res = {y2[ct][0], y2[ct][1], y2[ct][2], y2[ct][3]};
            *(f32x4*)(out + ((size_t)s * CC + cols[ct]) * NN + n0) = res;
        }
    }
}

// ---------------------------------------------------------------------------
// MFMA flash attention (r16 structure, prefetch depth 3): r7 staging,
// 2 q-tiles per wave, fixed-shift softmax, sequence-aligned split-K.
__global__ __launch_bounds__(256) void attn_mfma_kernel(
        const short* __restrict__ Qb, const short* __restrict__ Kh,
        const short* __restrict__ Vt, const float* __restrict__ kbw,
        short* __restrict__ pob, float* __restrict__ pl) {
    __shared__ short Kl[2][32][KROW];
    __shared__ short Vl[2][16][VROW];
    const int tid  = threadIdx.x;
    const int lane = tid & 63;
    const int wv   = tid >> 6;
    const int lq = lane & 15;
    const int g  = lane >> 4;
    const int h  = blockIdx.y;
    const int z  = blockIdx.z;
    const int qtA = blockIdx.x * 8 + wv * 2;
    const int qtB = qtA + 1;
    const bool qvA = qtA < LL / 16;
    const bool qvB = qtB < LL / 16;
    const int hd0 = h * 16;
    const int kbase = z * NN;

    bf16x4 qfA = {0, 0, 0, 0}, qfB = {0, 0, 0, 0};
    if (qvA) qfA = *(const bf16x4*)(Qb + (size_t)(qtA * 16 + lq) * CC + hd0 + 4 * g);
    if (qvB) qfB = *(const bf16x4*)(Qb + (size_t)(qtB * 16 + lq) * CC + hd0 + 4 * g);

    const short onev = (lq == 0) ? (short)0x3F80 : (short)0;
    const bf16x4 af1 = {onev, onev, onev, onev};

    const short* kgp = Kh + ((size_t)h * LL + kbase) * 16 + tid * 2;
    const short* vgp = Vt + (size_t)(hd0 + (tid >> 4)) * LL + kbase + (tid & 15) * 2;
    short* kwp = &Kl[0][0][0] + (tid >> 3) * KROW + (tid & 7) * 2;
    short* vwp = &Vl[0][0][0] + (tid >> 4) * VROW + (tid & 15) * 2;
    const int kbufstride = 32 * KROW;
    const int vbufstride = 16 * VROW;

    f32x4 oA  = {0.f, 0.f, 0.f, 0.f}, oB  = {0.f, 0.f, 0.f, 0.f};
    f32x4 psA = {0.f, 0.f, 0.f, 0.f}, psB = {0.f, 0.f, 0.f, 0.f};

    {   // prologue: stage tile 0 into buf 0; issue tiles 1,2 loads
        unsigned kd = *(const unsigned*)kgp;
        unsigned vd = *(const unsigned*)vgp;
        *(unsigned*)kwp = kd;
        *(unsigned*)vwp = vd;
    }
    unsigned kd1 = *(const unsigned*)(kgp + (size_t)1 * 32 * 16);
    unsigned vd1 = *(const unsigned*)(vgp + 1 * 32);
    unsigned kd2 = *(const unsigned*)(kgp + (size_t)2 * 32 * 16);
    unsigned vd2 = *(const unsigned*)(vgp + 2 * 32);
    __syncthreads();

    for (int t = 0; t < 31; ++t) {
        unsigned kd3, vd3;
        if (t < 29) {
            kd3 = *(const unsigned*)(kgp + (size_t)(t + 3) * 32 * 16);
            vd3 = *(const unsigned*)(vgp + (t + 3) * 32);
        }
        {
            const short* kb = &Kl[t & 1][0][0];
            const short* vb = &Vl[t & 1][0][0];
            bf16x4 K0 = *(const bf16x4*)(kb + lq * KROW + 4 * g);
            bf16x4 K1 = *(const bf16x4*)(kb + (16 + lq) * KROW + 4 * g);
            bf16x4 V0 = *(const bf16x4*)(vb + lq * VROW + 4 * g);
            bf16x4 V1 = *(const bf16x4*)(vb + lq * VROW + 16 + 4 * g);
            const f32x4 zz = {0.f, 0.f, 0.f, 0.f};
            f32x4 sA0 = __builtin_amdgcn_mfma_f32_16x16x16bf16_1k(K0, qfA, zz, 0, 0, 0);
            f32x4 sA1 = __builtin_amdgcn_mfma_f32_16x16x16bf16_1k(K1, qfA, zz, 0, 0, 0);
            f32x4 sB0 = __builtin_amdgcn_mfma_f32_16x16x16bf16_1k(K0, qfB, zz, 0, 0, 0);
            f32x4 sB1 = __builtin_amdgcn_mfma_f32_16x16x16bf16_1k(K1, qfB, zz, 0, 0, 0);
            float pA0[4], pA1[4], pB0[4], pB1[4];
            #pragma unroll
            for (int r = 0; r < 4; ++r) {
                pA0[r] = __builtin_amdgcn_exp2f(sA0[r]);
                pA1[r] = __builtin_amdgcn_exp2f(sA1[r]);
                pB0[r] = __builtin_amdgcn_exp2f(sB0[r]);
                pB1[r] = __builtin_amdgcn_exp2f(sB1[r]);
            }
            bf16x4 ptA0 = pack4(pA0), ptA1 = pack4(pA1);
            bf16x4 ptB0 = pack4(pB0), ptB1 = pack4(pB1);
            oA  = __builtin_amdgcn_mfma_f32_16x16x16bf16_1k(V0, ptA0, oA, 0, 0, 0);
            oA  = __builtin_amdgcn_mfma_f32_16x16x16bf16_1k(V1, ptA1, oA, 0, 0, 0);
            oB  = __builtin_amdgcn_mfma_f32_16x16x16bf16_1k(V0, ptB0, oB, 0, 0, 0);
            oB  = __builtin_amdgcn_mfma_f32_16x16x16bf16_1k(V1, ptB1, oB, 0, 0, 0);
            psA = __builtin_amdgcn_mfma_f32_16x16x16bf16_1k(af1, ptA0, psA, 0, 0, 0);
            psA = __builtin_amdgcn_mfma_f32_16x16x16bf16_1k(af1, ptA1, psA, 0, 0, 0);
            psB = __builtin_amdgcn_mfma_f32_16x16x16bf16_1k(af1, ptB0, psB, 0, 0, 0);
            psB = __builtin_amdgcn_mfma_f32_16x16x16bf16_1k(af1, ptB1, psB, 0, 0, 0);
        }
        const int nb = (t + 1) & 1;
        *(unsigned*)(kwp + nb * kbufstride) = kd1;
        *(unsigned*)(vwp + nb * vbufstride) = vd1;
        __syncthreads();
        kd1 = kd2; vd1 = vd2;
        if (t < 29) { kd2 = kd3; vd2 = vd3; }
    }

    {   // tail tile 31: local keys 992..999 valid; mask P (g>=2) AND V-frag
        const short* kb = &Kl[1][0][0];
        const short* vb = &Vl[1][0][0];
        bf16x4 K0 = *(const bf16x4*)(kb + lq * KROW + 4 * g);
        bf16x4 V0 = *(const bf16x4*)(vb + lq * VROW + 4 * g);
        if (g >= 2) V0 = (bf16x4){0, 0, 0, 0};
        const f32x4 zz = {0.f, 0.f, 0.f, 0.f};
        f32x4 sA0 = __builtin_amdgcn_mfma_f32_16x16x16bf16_1k(K0, qfA, zz, 0, 0, 0);
        f32x4 sB0 = __builtin_amdgcn_mfma_f32_16x16x16bf16_1k(K0, qfB, zz, 0, 0, 0);
        float pA0[4], pB0[4];
        #pragma unroll
        for (int r = 0; r < 4; ++r) {
            pA0[r] = (g < 2) ? __builtin_amdgcn_exp2f(sA0[r]) : 0.f;
            pB0[r] = (g < 2) ? __builtin_amdgcn_exp2f(sB0[r]) : 0.f;
        }
        bf16x4 ptA0 = pack4(pA0), ptB0 = pack4(pB0);
        oA  = __builtin_amdgcn_mfma_f32_16x16x16bf16_1k(V0, ptA0, oA, 0, 0, 0);
        oB  = __builtin_amdgcn_mfma_f32_16x16x16bf16_1k(V0, ptB0, oB, 0, 0, 0);
        psA = __builtin_amdgcn_mfma_f32_16x16x16bf16_1k(af1, ptA0, psA, 0, 0, 0);
        psB = __builtin_amdgcn_mfma_f32_16x16x16bf16_1k(af1, ptB0, psB, 0, 0, 0);
    }

    const float wz = kbw[z];
    if (qvA) {
        bf16x4 ow = {bf16rne(oA[0] * wz), bf16rne(oA[1] * wz),
                     bf16rne(oA[2] * wz), bf16rne(oA[3] * wz)};
        *(bf16x4*)(pob + (size_t)z * LL * CC + (size_t)(qtA * 16 + lq) * CC + hd0 + 4 * g) = ow;
        if (g == 0) pl[(z * 8 + h) * LL + qtA * 16 + lq] = psA[0] * wz;
    }
    if (qvB) {
        bf16x4 ow = {bf16rne(oB[0] * wz), bf16rne(oB[1] * wz),
                     bf16rne(oB[2] * wz), bf16rne(oB[3] * wz)};
        *(bf16x4*)(pob + (size_t)z * LL * CC + (size_t)(qtB * 16 + lq) * CC + hd0 + 4 * g) = ow;
        if (g == 0) pl[(z * 8 + h) * LL + qtB * 16 + lq] = psB[0] * wz;
    }
}

// ---------------------------------------------------------------------------
extern "C" void kernel_launch(void* const* d_in, const int* in_sizes, int n_in,
                              void* d_out, int out_size, void* d_ws, size_t ws_size,
                              hipStream_t stream) {
    const float* z    = (const float*)d_in[0];
    const float* r    = (const float*)d_in[1];
    const float* se   = (const float*)d_in[2];
    const float* Wq   = (const float*)d_in[3];
    const float* Wk   = (const float*)d_in[4];
    const float* Wv   = (const float*)d_in[5];
    const float* Wp   = (const float*)d_in[6];
    const float* beta = (const float*)d_in[7];
    const float* ln1g = (const float*)d_in[8];
    const float* ln1b = (const float*)d_in[9];
    const float* w1   = (const float*)d_in[10];
    const float* b1   = (const float*)d_in[11];
    const float* w2   = (const float*)d_in[12];
    const float* b2   = (const float*)d_in[13];
    const float* ln2g = (const float*)d_in[14];
    const float* ln2b = (const float*)d_in[15];
    float* out = (float*)d_out;

    float* ws   = (float*)d_ws;
    float* tok  = ws;                               // 512000 f
    float* kbw  = tok + LL * CC;                    // 8 f (16B aligned)
    float* pl   = kbw + 8;                          // KSPLIT*8*LL = 128000 f
    short* pob  = (short*)(pl + KSPLIT * 8 * LL);   // KSPLIT*LL*CC sh = 4 MB
    short* tokb = pob + (size_t)KSPLIT * LL * CC;
    short* Qb   = tokb + LL * CC;
    short* Kh   = Qb   + LL * CC;                   // head-major [H][L][16] + slack
    short* Vt   = Kh   + LL * CC + 1024;            // transposed [C][L] + slack
    short* wt8  = Vt   + LL * CC + 1024;
    short* w1t  = wt8  + 8 * 16384;
    short* w2t  = w1t  + 65536;

    const short* wq0 = wt8 + (size_t)0 * 16384;
    const short* wq1 = wt8 + (size_t)1 * 16384;
    const short* wk0 = wt8 + (size_t)2 * 16384;
    const short* wk1 = wt8 + (size_t)3 * 16384;
    const short* wv0 = wt8 + (size_t)4 * 16384;
    const short* wv1 = wt8 + (size_t)5 * 16384;
    const short* wp0 = wt8 + (size_t)6 * 16384;
    const short* wp1 = wt8 + (size_t)7 * 16384;

    prep_tok_kernel<<<1537, 256, 0, stream>>>(Wq, Wk, Wv, Wp, w1, w2, r, beta,
                                              wt8, w1t, w2t, kbw, z, se, tok, tokb);

    // layer 0 QKV
    mfma_gemm3<<<dim3(LL / 16, 1, 3), 256, 0, stream>>>(
        tokb, wq0, wk0, wv0, Qb, Kh, Vt, LL, CC, CC);
    // layer 0 attention
    attn_mfma_kernel<<<dim3((LL / 16 + 7) / 8, 8, KSPLIT), 256, 0, stream>>>(
        Qb, Kh, Vt, kbw + 0 * KSPLIT, pob, pl);
    // layer 0 proj+LN fused with layer 1 QKV
    mfma_cmb_ln_qkv<<<LL / 16, 256, 0, stream>>>(
        pob, pl, wp0, tok, ln1g + 0 * CC, ln1b + 0 * CC, tok,
        wq1, wk1, wv1, Qb, Kh, Vt);
    // layer 1 attention
    attn_mfma_kernel<<<dim3((LL / 16 + 7) / 8, 8, KSPLIT), 256, 0, stream>>>(
        Qb, Kh, Vt, kbw + 1 * KSPLIT, pob, pl);
    // layer 1 proj+LN fused with FFN + LN2 + detokenize (writes d_out directly)
    mfma_cmb_ln_ffn<<<LL / 16, 256, 0, stream>>>(
        pob, pl, wp1, tok, ln1g + 1 * CC, ln1b + 1 * CC,
        w1t, b1, w2t, b2, ln2g, ln2b, out);
}